// Round 5
// baseline (897.630 us; speedup 1.0000x reference)
//
#include <hip/hip_runtime.h>
#include <hip/hip_bf16.h>
#include <math.h>

// ---------------------------------------------------------------------------
// SimpleBetterGCN, R5.
//   xb  = bf16(x)                         [N,64]
//   ax  = A @ xb (spmm1), rs = rowsum(A)
//   h1r = relu(ax@W1 + rs*b1)  (bf16)     [N,128]
//   t2  = bf16(h1r@W2 + b2)               [N,128]
//   h2p = A @ t2 (spmm2)        f32       [N,128]
//   attention: online softmax over nodes of (h1r + relu(h2p)), fused.
//
// Measured model: gather line-rate ceiling ~76 G lines/s (4.9 TB/s) for the
// random-row gather; spmm2 (4 lines/edge) sits AT it. spmm1 (2 lines/edge) was
// VMEM-instruction-issue bound (~4 instr/edge); R5 packs 4 edges per gather
// instruction (quarter-wave, 16 lanes x 8B = 128-B row) and batches metadata
// via one coalesced load per 64 edges + __shfl.
// ---------------------------------------------------------------------------

#define HID 128

__device__ __forceinline__ float relu(float v) { return v > 0.f ? v : 0.f; }

__device__ __forceinline__ unsigned short f2bf(float f) {
  unsigned u = __float_as_uint(f);
  u += 0x7FFFu + ((u >> 16) & 1u);
  return (unsigned short)(u >> 16);
}
__device__ __forceinline__ float bflo(unsigned u) {
  return __uint_as_float(u << 16);
}
__device__ __forceinline__ float bfhi(unsigned u) {
  return __uint_as_float(u & 0xFFFF0000u);
}

// --------------------------- cast x -> bf16 --------------------------------
__global__ __launch_bounds__(256) void cast_x_kernel(
    const float* __restrict__ x, unsigned short* __restrict__ xb, int n4) {
  int idx = blockIdx.x * 256 + threadIdx.x;
  if (idx < n4) {
    float4 v = *(const float4*)&x[idx * 4];
    ushort4 o;
    o.x = f2bf(v.x); o.y = f2bf(v.y); o.z = f2bf(v.z); o.w = f2bf(v.w);
    *(ushort4*)&xb[idx * 4] = o;
  }
}

// --------------------------- SPMM1 (64-dim bf16, quarter-wave) -------------
// ax[r,:] += v * xb[c,:]; rs[r] += v.
// Quarter-wave: lanes 16q..16q+15 handle edge j+q; each lane 4 dims (dwordx2).
// One gather instruction covers 4 edges. 2x unroll => 8 edges / 2 gathers.
__global__ __launch_bounds__(256) void spmm1_kernel(
    const unsigned short* __restrict__ mat, const int* __restrict__ rows,
    const int* __restrict__ cols, const float* __restrict__ vals,
    float* __restrict__ ax, float* __restrict__ rs, int E) {
  int gw0 = (blockIdx.x * blockDim.x + threadIdx.x) >> 6;
  const int gw = __builtin_amdgcn_readfirstlane(gw0);
  const int lane = threadIdx.x & 63;
  const int nw = (gridDim.x * blockDim.x) >> 6;
  const int S = (E + nw - 1) / nw;
  int start = gw * S;
  int end = start + S;
  if (end > E) end = E;
  if (start >= end) return;

  const int q = lane >> 4;        // quarter 0..3 -> edge j+q
  const int ql = lane & 15;       // lane in quarter
  const int d4 = ql * 4;          // dims d4..d4+3
  float4 acc = {0.f, 0.f, 0.f, 0.f};
  float accv = 0.f;
  int curRow = rows[start];

  auto flush = [&]() {
    float* o = ax + (size_t)curRow * 64 + d4;
    atomicAdd(o + 0, acc.x);
    atomicAdd(o + 1, acc.y);
    atomicAdd(o + 2, acc.z);
    atomicAdd(o + 3, acc.w);
    if (ql == 0) atomicAdd(rs + curRow, accv);
    acc.x = acc.y = acc.z = acc.w = 0.f;
    accv = 0.f;
  };

  for (int base = start; base < end; base += 64) {
    const int cnt = min(64, end - base);
    int c_ = 0, r_ = 0;
    float v_ = 0.f;
    if (lane < cnt) {
      int e = base + lane;
      c_ = cols[e];
      v_ = vals[e];
      r_ = rows[e];
    }

    int j = 0;
    // main: 8 edges per iteration, 2 gathers in flight
    for (; j + 8 <= cnt; j += 8) {
      int i0 = j + q, i1 = j + 4 + q;
      int c0 = __shfl(c_, i0), c1 = __shfl(c_, i1);
      float v0 = __shfl(v_, i0), v1 = __shfl(v_, i1);
      int r0 = __shfl(r_, i0), r1 = __shfl(r_, i1);
      uint2 u0 = *(const uint2*)(mat + (size_t)c0 * 64 + d4);
      uint2 u1 = *(const uint2*)(mat + (size_t)c1 * 64 + d4);

      if (r0 != curRow) { flush(); curRow = r0; }
      acc.x = fmaf(v0, bflo(u0.x), acc.x);
      acc.y = fmaf(v0, bfhi(u0.x), acc.y);
      acc.z = fmaf(v0, bflo(u0.y), acc.z);
      acc.w = fmaf(v0, bfhi(u0.y), acc.w);
      accv += v0;
      if (r1 != curRow) { flush(); curRow = r1; }
      acc.x = fmaf(v1, bflo(u1.x), acc.x);
      acc.y = fmaf(v1, bfhi(u1.x), acc.y);
      acc.z = fmaf(v1, bflo(u1.y), acc.z);
      acc.w = fmaf(v1, bfhi(u1.y), acc.w);
      accv += v1;
    }
    // tail: 4 edges per iteration, predicated
    for (; j < cnt; j += 4) {
      int idx = j + q;
      bool valid = idx < cnt;
      int ii = valid ? idx : (cnt - 1);
      int c = __shfl(c_, ii);
      float v = __shfl(v_, ii);
      int r = __shfl(r_, ii);
      if (!valid) { v = 0.f; r = curRow; }
      if (r != curRow) { flush(); curRow = r; }
      uint2 u = *(const uint2*)(mat + (size_t)c * 64 + d4);
      acc.x = fmaf(v, bflo(u.x), acc.x);
      acc.y = fmaf(v, bfhi(u.x), acc.y);
      acc.z = fmaf(v, bflo(u.y), acc.z);
      acc.w = fmaf(v, bfhi(u.y), acc.w);
      accv += v;
    }
  }
  flush();
}

// --------------------------- gemm1: h1r = relu(ax@W1 + rs*b1) (bf16) -------
__global__ __launch_bounds__(256) void gemm1_kernel(
    const float* __restrict__ ax, const float* __restrict__ w1,
    const float* __restrict__ b1, const float* __restrict__ rs,
    unsigned short* __restrict__ h1r, int N) {
  __shared__ float w_lds[64 * HID];     // 32 KB
  __shared__ float in_lds[64 * 64];     // 16 KB
  __shared__ float rs_lds[64];
  const int t = threadIdx.x;
  const int R0 = blockIdx.x * 64;

  for (int idx = t * 4; idx < 64 * HID; idx += 1024)
    *(float4*)&w_lds[idx] = *(const float4*)&w1[idx];
  const int limit = N * 64;
  for (int idx = t * 4; idx < 64 * 64; idx += 1024) {
    int g = R0 * 64 + idx;
    float4 v;
    if (g < limit) v = *(const float4*)&ax[g];
    else { v.x = v.y = v.z = v.w = 0.f; }
    *(float4*)&in_lds[idx] = v;
  }
  if (t < 64) {
    int gr = R0 + t;
    rs_lds[t] = gr < N ? rs[gr] : 0.f;
  }
  __syncthreads();

  const int i = t >> 5, j = t & 31;
  const int r0 = i * 8, c0 = j * 4;
  float4 bv = *(const float4*)&b1[c0];
  float acc[8][4] = {};

#pragma unroll 4
  for (int k = 0; k < 64; ++k) {
    float4 wv = *(const float4*)&w_lds[k * HID + c0];
#pragma unroll
    for (int ii = 0; ii < 8; ++ii) {
      float a = in_lds[(r0 + ii) * 64 + k];
      acc[ii][0] = fmaf(a, wv.x, acc[ii][0]);
      acc[ii][1] = fmaf(a, wv.y, acc[ii][1]);
      acc[ii][2] = fmaf(a, wv.z, acc[ii][2]);
      acc[ii][3] = fmaf(a, wv.w, acc[ii][3]);
    }
  }

#pragma unroll
  for (int ii = 0; ii < 8; ++ii) {
    int gr = R0 + r0 + ii;
    if (gr < N) {
      float rsv = rs_lds[r0 + ii];
      ushort4 o;
      o.x = f2bf(relu(acc[ii][0] + rsv * bv.x));
      o.y = f2bf(relu(acc[ii][1] + rsv * bv.y));
      o.z = f2bf(relu(acc[ii][2] + rsv * bv.z));
      o.w = f2bf(relu(acc[ii][3] + rsv * bv.w));
      *(ushort4*)&h1r[(size_t)gr * HID + c0] = o;
    }
  }
}

// --------------------------- gemm2: t2 = bf16(h1r@W2 + b2) -----------------
__global__ __launch_bounds__(256) void gemm2_kernel(
    const unsigned short* __restrict__ h1r, const float* __restrict__ w2,
    const float* __restrict__ b2, unsigned short* __restrict__ t2, int N) {
  __shared__ unsigned short w_lds[HID * HID];   // 32 KB
  __shared__ unsigned short in_lds[64 * HID];   // 16 KB
  const int t = threadIdx.x;
  const int R0 = blockIdx.x * 64;

  for (int idx = t * 4; idx < HID * HID; idx += 1024) {
    float4 v = *(const float4*)&w2[idx];
    ushort4 o;
    o.x = f2bf(v.x); o.y = f2bf(v.y); o.z = f2bf(v.z); o.w = f2bf(v.w);
    *(ushort4*)&w_lds[idx] = o;
  }
  const size_t limit = (size_t)N * HID;
  for (int idx = t * 8; idx < 64 * HID; idx += 2048) {
    size_t g = (size_t)R0 * HID + idx;
    uint4 v;
    if (g < limit) v = *(const uint4*)&h1r[g];
    else { v.x = v.y = v.z = v.w = 0u; }
    *(uint4*)&in_lds[idx] = v;
  }
  __syncthreads();

  const int i = t >> 5, j = t & 31;
  const int r0 = i * 8, c0 = j * 4;
  float acc[8][4] = {};

#pragma unroll 2
  for (int k = 0; k < HID; k += 2) {
    ushort4 wu0 = *(const ushort4*)&w_lds[k * HID + c0];
    ushort4 wu1 = *(const ushort4*)&w_lds[(k + 1) * HID + c0];
    float w0x = bflo(wu0.x), w0y = bflo(wu0.y), w0z = bflo(wu0.z), w0w = bflo(wu0.w);
    float w1x = bflo(wu1.x), w1y = bflo(wu1.y), w1z = bflo(wu1.z), w1w = bflo(wu1.w);
#pragma unroll
    for (int ii = 0; ii < 8; ++ii) {
      unsigned au = *(const unsigned*)&in_lds[(r0 + ii) * HID + k];
      float a0 = bflo(au), a1 = bfhi(au);
      acc[ii][0] = fmaf(a1, w1x, fmaf(a0, w0x, acc[ii][0]));
      acc[ii][1] = fmaf(a1, w1y, fmaf(a0, w0y, acc[ii][1]));
      acc[ii][2] = fmaf(a1, w1z, fmaf(a0, w0z, acc[ii][2]));
      acc[ii][3] = fmaf(a1, w1w, fmaf(a0, w0w, acc[ii][3]));
    }
  }

  float4 bv = *(const float4*)&b2[c0];
#pragma unroll
  for (int ii = 0; ii < 8; ++ii) {
    int gr = R0 + r0 + ii;
    if (gr < N) {
      ushort4 o;
      o.x = f2bf(acc[ii][0] + bv.x);
      o.y = f2bf(acc[ii][1] + bv.y);
      o.z = f2bf(acc[ii][2] + bv.z);
      o.w = f2bf(acc[ii][3] + bv.w);
      *(ushort4*)&t2[(size_t)gr * HID + c0] = o;
    }
  }
}

// --------------------------- SPMM2 (128-dim bf16, full wave) ---------------
// Line-rate-bound (4 lines/edge at ~76 G lines/s). Metadata batched via
// coalesced per-lane loads + shfl broadcast to free the VMEM pipe.
__global__ __launch_bounds__(256) void spmm2_kernel(
    const unsigned short* __restrict__ mat, const int* __restrict__ rows,
    const int* __restrict__ cols, const float* __restrict__ vals,
    float* __restrict__ out, int E) {
  int gw0 = (blockIdx.x * blockDim.x + threadIdx.x) >> 6;
  const int gw = __builtin_amdgcn_readfirstlane(gw0);
  const int lane = threadIdx.x & 63;
  const int nw = (gridDim.x * blockDim.x) >> 6;
  const int S = (E + nw - 1) / nw;
  int start = gw * S;
  int end = start + S;
  if (end > E) end = E;
  if (start >= end) return;

  const int d2 = lane * 2;
  float2 acc = {0.f, 0.f};
  int curRow = rows[start];

  auto flush = [&]() {
    float* o = out + (size_t)curRow * HID + d2;
    atomicAdd(o + 0, acc.x);
    atomicAdd(o + 1, acc.y);
    acc.x = 0.f;
    acc.y = 0.f;
  };

  for (int base = start; base < end; base += 64) {
    const int cnt = min(64, end - base);
    int c_ = 0, r_ = 0;
    float v_ = 0.f;
    if (lane < cnt) {
      int e = base + lane;
      c_ = cols[e];
      v_ = vals[e];
      r_ = rows[e];
    }

    int j = 0;
    for (; j + 4 <= cnt; j += 4) {
      int c0 = __shfl(c_, j + 0), c1 = __shfl(c_, j + 1);
      int c2 = __shfl(c_, j + 2), c3 = __shfl(c_, j + 3);
      float v0 = __shfl(v_, j + 0), v1 = __shfl(v_, j + 1);
      float v2 = __shfl(v_, j + 2), v3 = __shfl(v_, j + 3);
      int r0 = __shfl(r_, j + 0), r1 = __shfl(r_, j + 1);
      int r2 = __shfl(r_, j + 2), r3 = __shfl(r_, j + 3);
      unsigned u0 = *(const unsigned*)(mat + (size_t)c0 * HID + d2);
      unsigned u1 = *(const unsigned*)(mat + (size_t)c1 * HID + d2);
      unsigned u2 = *(const unsigned*)(mat + (size_t)c2 * HID + d2);
      unsigned u3 = *(const unsigned*)(mat + (size_t)c3 * HID + d2);

      if (r0 != curRow) { flush(); curRow = r0; }
      acc.x = fmaf(v0, bflo(u0), acc.x);
      acc.y = fmaf(v0, bfhi(u0), acc.y);
      if (r1 != curRow) { flush(); curRow = r1; }
      acc.x = fmaf(v1, bflo(u1), acc.x);
      acc.y = fmaf(v1, bfhi(u1), acc.y);
      if (r2 != curRow) { flush(); curRow = r2; }
      acc.x = fmaf(v2, bflo(u2), acc.x);
      acc.y = fmaf(v2, bfhi(u2), acc.y);
      if (r3 != curRow) { flush(); curRow = r3; }
      acc.x = fmaf(v3, bflo(u3), acc.x);
      acc.y = fmaf(v3, bfhi(u3), acc.y);
    }
    for (; j < cnt; ++j) {
      int c = __shfl(c_, j);
      float v = __shfl(v_, j);
      int r = __shfl(r_, j);
      if (r != curRow) { flush(); curRow = r; }
      unsigned u = *(const unsigned*)(mat + (size_t)c * HID + d2);
      acc.x = fmaf(v, bflo(u), acc.x);
      acc.y = fmaf(v, bfhi(u), acc.y);
    }
  }
  flush();
}

// --------------------------- fused attention (online softmax) --------------
// Per wave: grid-stride over nodes, score + online-softmax accumulation of
// den and num[128] in registers; block combine in LDS -> one partial/block.
// Partials: pm[b], pden[b], pnum[c*NB + b] (component-major).
__global__ __launch_bounds__(256) void att_fused_kernel(
    const unsigned short* __restrict__ h1r, const float* __restrict__ h2p,
    const float* __restrict__ attw, const float* __restrict__ attb,
    float* __restrict__ pm, float* __restrict__ pden,
    float* __restrict__ pnum, int N) {
  __shared__ float sm[4], sden[4], snum[4][HID];
  const int NB = gridDim.x;
  const int w = threadIdx.x >> 6;
  const int lane = threadIdx.x & 63;
  const int gw = blockIdx.x * 4 + w;
  const int nw = NB * 4;
  const float2 wv = *(const float2*)(attw + lane * 2);
  const float b = attb[0];

  float m = -INFINITY, den = 0.f, ax = 0.f, ay = 0.f;
  for (int n = gw; n < N; n += nw) {
    unsigned hu = *(const unsigned*)&h1r[(size_t)n * HID + lane * 2];
    float2 c = *(const float2*)&h2p[(size_t)n * HID + lane * 2];
    float hx = bflo(hu) + relu(c.x);
    float hy = bfhi(hu) + relu(c.y);
    float p = hx * wv.x + hy * wv.y;
#pragma unroll
    for (int off = 1; off < 64; off <<= 1) p += __shfl_xor(p, off);
    float sc = p + b;
    if (sc > m) {
      float scale = expf(m - sc);   // exp(-inf)=0 on first node
      den *= scale; ax *= scale; ay *= scale;
      m = sc;
    }
    float e = expf(sc - m);
    den += e;
    ax = fmaf(e, hx, ax);
    ay = fmaf(e, hy, ay);
  }

  if (lane == 0) { sm[w] = m; sden[w] = den; }
  snum[w][lane * 2] = ax;
  snum[w][lane * 2 + 1] = ay;
  __syncthreads();

  const int t = threadIdx.x;
  if (t < HID) {
    float M4 = fmaxf(fmaxf(sm[0], sm[1]), fmaxf(sm[2], sm[3]));
    float s0 = expf(sm[0] - M4), s1 = expf(sm[1] - M4);
    float s2 = expf(sm[2] - M4), s3 = expf(sm[3] - M4);
    float nv = snum[0][t] * s0 + snum[1][t] * s1 + snum[2][t] * s2 +
               snum[3][t] * s3;
    pnum[(size_t)t * NB + blockIdx.x] = nv;
    if (t == 0) {
      pden[blockIdx.x] = sden[0] * s0 + sden[1] * s1 + sden[2] * s2 +
                         sden[3] * s3;
      pm[blockIdx.x] = M4;
    }
  }
}

// --------------------------- combine partials + classifier -----------------
// One block of 1024; NB must equal 1024.
__global__ __launch_bounds__(1024) void att_combine_kernel(
    const float* __restrict__ pm, const float* __restrict__ pden,
    const float* __restrict__ pnum, const float* __restrict__ clsw,
    const float* __restrict__ clsb, float* __restrict__ out, int NB) {
  __shared__ float red[1024];
  __shared__ float scale[1024];
  __shared__ float g[HID + 1];  // [0..127]=num, [128]=den
  const int t = threadIdx.x;

  float v = pm[t];
  red[t] = v;
  __syncthreads();
  for (int off = 512; off > 0; off >>= 1) {
    if (t < off) red[t] = fmaxf(red[t], red[t + off]);
    __syncthreads();
  }
  const float M = red[0];
  __syncthreads();

  scale[t] = expf(v - M);
  red[t] = pden[t] * scale[t];
  __syncthreads();
  for (int off = 512; off > 0; off >>= 1) {
    if (t < off) red[t] += red[t + off];
    __syncthreads();
  }
  if (t == 0) g[HID] = red[0];

  // num: 128 components x 8 threads each
  const int c = t >> 3, bb = t & 7;
  float acc = 0.f;
  for (int b2 = bb; b2 < NB; b2 += 8) acc += pnum[(size_t)c * NB + b2] * scale[b2];
  acc += __shfl_down(acc, 4);
  acc += __shfl_down(acc, 2);
  acc += __shfl_down(acc, 1);
  if (bb == 0) g[c] = acc;
  __syncthreads();

  if (t < 10) {
    float o = 0.f;
    for (int d = 0; d < HID; ++d) o = fmaf(g[d], clsw[d * 10 + t], o);
    out[t] = clsb[t] + o / g[HID];
  }
}

extern "C" void kernel_launch(void* const* d_in, const int* in_sizes, int n_in,
                              void* d_out, int out_size, void* d_ws,
                              size_t ws_size, hipStream_t stream) {
  const float* x = (const float*)d_in[0];
  const int* erows = (const int*)d_in[1];
  const int* ecols = (const int*)d_in[2];
  const float* evals = (const float*)d_in[3];
  const float* fc1w = (const float*)d_in[4];
  const float* fc1b = (const float*)d_in[5];
  const float* fc2w = (const float*)d_in[6];
  const float* fc2b = (const float*)d_in[7];
  const float* attw = (const float*)d_in[8];
  const float* attb = (const float*)d_in[9];
  const float* clsw = (const float*)d_in[10];
  const float* clsb = (const float*)d_in[11];
  float* out = (float*)d_out;

  const int N = in_sizes[0] / 64;   // 100000
  const int E = in_sizes[1];        // 3200000
  const int NB = 1024;              // attention partial blocks

  char* base = (char*)d_ws;
  float* ax = (float*)base;                                      // N*64 f32
  float* h2p = (float*)(base + (size_t)N * 64 * 4);              // N*128 f32
  float* rs = (float*)(base + (size_t)N * (64 + 128) * 4);       // N f32
  unsigned short* xb = (unsigned short*)(base + (size_t)N * (64 + 128 + 1) * 4);
  unsigned short* t2 = (unsigned short*)((char*)xb + (size_t)N * 64 * 2);
  unsigned short* h1r = (unsigned short*)((char*)t2 + (size_t)N * HID * 2);
  float* pm = (float*)((char*)h1r + (size_t)N * HID * 2);        // NB
  float* pden = pm + NB;                                         // NB
  float* pnum = pden + NB;                                       // 128*NB

  const int nblk = (N + 63) / 64;

  // Zero accumulators: ax | h2p | rs are contiguous.
  hipMemsetAsync(ax, 0, (size_t)N * (64 + 128 + 1) * 4, stream);

  cast_x_kernel<<<(N * 64 / 4 + 255) / 256, 256, 0, stream>>>(x, xb, N * 16);
  spmm1_kernel<<<2048, 256, 0, stream>>>(xb, erows, ecols, evals, ax, rs, E);
  gemm1_kernel<<<nblk, 256, 0, stream>>>(ax, fc1w, fc1b, rs, h1r, N);
  gemm2_kernel<<<nblk, 256, 0, stream>>>(h1r, fc2w, fc2b, t2, N);
  spmm2_kernel<<<2048, 256, 0, stream>>>(t2, erows, ecols, evals, h2p, E);
  att_fused_kernel<<<NB, 256, 0, stream>>>(h1r, h2p, attw, attb, pm, pden,
                                           pnum, N);
  att_combine_kernel<<<1, 1024, 0, stream>>>(pm, pden, pnum, clsw, clsb, out,
                                             NB);
}

// Round 6
// 522.902 us; speedup vs baseline: 1.7166x; 1.7166x over previous
//
#include <hip/hip_runtime.h>
#include <hip/hip_bf16.h>
#include <math.h>

// ---------------------------------------------------------------------------
// SimpleBetterGCN, R6.
//   xb  = bf16(x)                         [N,64]
//   ax  = A @ xb (spmm1), rs = rowsum(A)
//   h1r = relu(ax@W1 + rs*b1)  (bf16)     [N,128]
//   t2  = bf16(h1r@W2 + b2)               [N,128]
//   h2p = A @ t2 (spmm2)        f32       [N,128]
//   attention: online softmax over nodes of (h1r + relu(h2p)), fused.
//
// Model (R1-R5 evidence): spmm cost = max(per-edge latency chain, line rate
// ~76 G lines/s). spmm2 sits at its line floor (4 lines/edge -> 168 us).
// spmm1 (2 lines/edge, floor 84 us) was chain-bound at 168 us; R6 breaks the
// chain: batch metadata (1 coalesced load / 64 edges + readlane distribute)
// and 8 gathers in flight. Flush stays FULL-WAVE (single curRow) — R2/R5
// proved sub-wave edge splitting multiplies atomic flush traffic 4x.
// ---------------------------------------------------------------------------

#define HID 128

__device__ __forceinline__ float relu(float v) { return v > 0.f ? v : 0.f; }

__device__ __forceinline__ unsigned short f2bf(float f) {
  unsigned u = __float_as_uint(f);
  u += 0x7FFFu + ((u >> 16) & 1u);
  return (unsigned short)(u >> 16);
}
__device__ __forceinline__ float bflo(unsigned u) {
  return __uint_as_float(u << 16);
}
__device__ __forceinline__ float bfhi(unsigned u) {
  return __uint_as_float(u & 0xFFFF0000u);
}

// --------------------------- cast x -> bf16 --------------------------------
__global__ __launch_bounds__(256) void cast_x_kernel(
    const float* __restrict__ x, unsigned short* __restrict__ xb, int n4) {
  int idx = blockIdx.x * 256 + threadIdx.x;
  if (idx < n4) {
    float4 v = *(const float4*)&x[idx * 4];
    ushort4 o;
    o.x = f2bf(v.x); o.y = f2bf(v.y); o.z = f2bf(v.z); o.w = f2bf(v.w);
    *(ushort4*)&xb[idx * 4] = o;
  }
}

// --------------------------- SPMM1 (64-dim bf16, full wave) ----------------
// ax[r,:] += v * xb[c,:]; rs[r] += v.  One dim per lane (128B row).
// Metadata: one coalesced per-lane load per 64-edge batch, distributed via
// __shfl (uniform index -> v_readlane, scalar pipe).  8 gathers in flight.
__global__ __launch_bounds__(256) void spmm1_kernel(
    const unsigned short* __restrict__ mat, const int* __restrict__ rows,
    const int* __restrict__ cols, const float* __restrict__ vals,
    float* __restrict__ ax, float* __restrict__ rs, int E) {
  int gw0 = (blockIdx.x * blockDim.x + threadIdx.x) >> 6;
  const int gw = __builtin_amdgcn_readfirstlane(gw0);
  const int lane = threadIdx.x & 63;
  const int nw = (gridDim.x * blockDim.x) >> 6;
  const int S = (E + nw - 1) / nw;
  int start = gw * S;
  int end = start + S;
  if (end > E) end = E;
  if (start >= end) return;

  float acc = 0.f, accv = 0.f;
  int curRow = rows[start];

  auto flush = [&]() {
    atomicAdd(ax + (size_t)curRow * 64 + lane, acc);
    if (lane == 0) atomicAdd(rs + curRow, accv);
    acc = 0.f;
    accv = 0.f;
  };

  for (int base = start; base < end; base += 64) {
    const int cnt = min(64, end - base);
    int c_ = 0, r_ = 0;
    float v_ = 0.f;
    if (lane < cnt) {
      int e = base + lane;
      c_ = cols[e];
      v_ = vals[e];
      r_ = rows[e];
    }

    int j = 0;
    for (; j + 8 <= cnt; j += 8) {
      int c0 = __shfl(c_, j + 0), c1 = __shfl(c_, j + 1);
      int c2 = __shfl(c_, j + 2), c3 = __shfl(c_, j + 3);
      int c4 = __shfl(c_, j + 4), c5 = __shfl(c_, j + 5);
      int c6 = __shfl(c_, j + 6), c7 = __shfl(c_, j + 7);
      // 8 independent gathers in flight
      unsigned u0 = mat[(size_t)c0 * 64 + lane];
      unsigned u1 = mat[(size_t)c1 * 64 + lane];
      unsigned u2 = mat[(size_t)c2 * 64 + lane];
      unsigned u3 = mat[(size_t)c3 * 64 + lane];
      unsigned u4 = mat[(size_t)c4 * 64 + lane];
      unsigned u5 = mat[(size_t)c5 * 64 + lane];
      unsigned u6 = mat[(size_t)c6 * 64 + lane];
      unsigned u7 = mat[(size_t)c7 * 64 + lane];

      float v0 = __shfl(v_, j + 0), v1 = __shfl(v_, j + 1);
      float v2 = __shfl(v_, j + 2), v3 = __shfl(v_, j + 3);
      float v4 = __shfl(v_, j + 4), v5 = __shfl(v_, j + 5);
      float v6 = __shfl(v_, j + 6), v7 = __shfl(v_, j + 7);
      int r0 = __shfl(r_, j + 0), r1 = __shfl(r_, j + 1);
      int r2 = __shfl(r_, j + 2), r3 = __shfl(r_, j + 3);
      int r4 = __shfl(r_, j + 4), r5 = __shfl(r_, j + 5);
      int r6 = __shfl(r_, j + 6), r7 = __shfl(r_, j + 7);

      if (r0 != curRow) { flush(); curRow = r0; }
      acc = fmaf(v0, bflo(u0), acc); accv += v0;
      if (r1 != curRow) { flush(); curRow = r1; }
      acc = fmaf(v1, bflo(u1), acc); accv += v1;
      if (r2 != curRow) { flush(); curRow = r2; }
      acc = fmaf(v2, bflo(u2), acc); accv += v2;
      if (r3 != curRow) { flush(); curRow = r3; }
      acc = fmaf(v3, bflo(u3), acc); accv += v3;
      if (r4 != curRow) { flush(); curRow = r4; }
      acc = fmaf(v4, bflo(u4), acc); accv += v4;
      if (r5 != curRow) { flush(); curRow = r5; }
      acc = fmaf(v5, bflo(u5), acc); accv += v5;
      if (r6 != curRow) { flush(); curRow = r6; }
      acc = fmaf(v6, bflo(u6), acc); accv += v6;
      if (r7 != curRow) { flush(); curRow = r7; }
      acc = fmaf(v7, bflo(u7), acc); accv += v7;
    }
    for (; j < cnt; ++j) {
      int c = __shfl(c_, j);
      float v = __shfl(v_, j);
      int r = __shfl(r_, j);
      if (r != curRow) { flush(); curRow = r; }
      unsigned u = mat[(size_t)c * 64 + lane];
      acc = fmaf(v, bflo(u), acc); accv += v;
    }
  }
  flush();
}

// --------------------------- gemm1: h1r = relu(ax@W1 + rs*b1) (bf16) -------
__global__ __launch_bounds__(256) void gemm1_kernel(
    const float* __restrict__ ax, const float* __restrict__ w1,
    const float* __restrict__ b1, const float* __restrict__ rs,
    unsigned short* __restrict__ h1r, int N) {
  __shared__ float w_lds[64 * HID];     // 32 KB
  __shared__ float in_lds[64 * 64];     // 16 KB
  __shared__ float rs_lds[64];
  const int t = threadIdx.x;
  const int R0 = blockIdx.x * 64;

  for (int idx = t * 4; idx < 64 * HID; idx += 1024)
    *(float4*)&w_lds[idx] = *(const float4*)&w1[idx];
  const int limit = N * 64;
  for (int idx = t * 4; idx < 64 * 64; idx += 1024) {
    int g = R0 * 64 + idx;
    float4 v;
    if (g < limit) v = *(const float4*)&ax[g];
    else { v.x = v.y = v.z = v.w = 0.f; }
    *(float4*)&in_lds[idx] = v;
  }
  if (t < 64) {
    int gr = R0 + t;
    rs_lds[t] = gr < N ? rs[gr] : 0.f;
  }
  __syncthreads();

  const int i = t >> 5, j = t & 31;
  const int r0 = i * 8, c0 = j * 4;
  float4 bv = *(const float4*)&b1[c0];
  float acc[8][4] = {};

#pragma unroll 4
  for (int k = 0; k < 64; ++k) {
    float4 wv = *(const float4*)&w_lds[k * HID + c0];
#pragma unroll
    for (int ii = 0; ii < 8; ++ii) {
      float a = in_lds[(r0 + ii) * 64 + k];
      acc[ii][0] = fmaf(a, wv.x, acc[ii][0]);
      acc[ii][1] = fmaf(a, wv.y, acc[ii][1]);
      acc[ii][2] = fmaf(a, wv.z, acc[ii][2]);
      acc[ii][3] = fmaf(a, wv.w, acc[ii][3]);
    }
  }

#pragma unroll
  for (int ii = 0; ii < 8; ++ii) {
    int gr = R0 + r0 + ii;
    if (gr < N) {
      float rsv = rs_lds[r0 + ii];
      ushort4 o;
      o.x = f2bf(relu(acc[ii][0] + rsv * bv.x));
      o.y = f2bf(relu(acc[ii][1] + rsv * bv.y));
      o.z = f2bf(relu(acc[ii][2] + rsv * bv.z));
      o.w = f2bf(relu(acc[ii][3] + rsv * bv.w));
      *(ushort4*)&h1r[(size_t)gr * HID + c0] = o;
    }
  }
}

// --------------------------- gemm2: t2 = bf16(h1r@W2 + b2) -----------------
__global__ __launch_bounds__(256) void gemm2_kernel(
    const unsigned short* __restrict__ h1r, const float* __restrict__ w2,
    const float* __restrict__ b2, unsigned short* __restrict__ t2, int N) {
  __shared__ unsigned short w_lds[HID * HID];   // 32 KB
  __shared__ unsigned short in_lds[64 * HID];   // 16 KB
  const int t = threadIdx.x;
  const int R0 = blockIdx.x * 64;

  for (int idx = t * 4; idx < HID * HID; idx += 1024) {
    float4 v = *(const float4*)&w2[idx];
    ushort4 o;
    o.x = f2bf(v.x); o.y = f2bf(v.y); o.z = f2bf(v.z); o.w = f2bf(v.w);
    *(ushort4*)&w_lds[idx] = o;
  }
  const size_t limit = (size_t)N * HID;
  for (int idx = t * 8; idx < 64 * HID; idx += 2048) {
    size_t g = (size_t)R0 * HID + idx;
    uint4 v;
    if (g < limit) v = *(const uint4*)&h1r[g];
    else { v.x = v.y = v.z = v.w = 0u; }
    *(uint4*)&in_lds[idx] = v;
  }
  __syncthreads();

  const int i = t >> 5, j = t & 31;
  const int r0 = i * 8, c0 = j * 4;
  float acc[8][4] = {};

#pragma unroll 2
  for (int k = 0; k < HID; k += 2) {
    ushort4 wu0 = *(const ushort4*)&w_lds[k * HID + c0];
    ushort4 wu1 = *(const ushort4*)&w_lds[(k + 1) * HID + c0];
    float w0x = bflo(wu0.x), w0y = bflo(wu0.y), w0z = bflo(wu0.z), w0w = bflo(wu0.w);
    float w1x = bflo(wu1.x), w1y = bflo(wu1.y), w1z = bflo(wu1.z), w1w = bflo(wu1.w);
#pragma unroll
    for (int ii = 0; ii < 8; ++ii) {
      unsigned au = *(const unsigned*)&in_lds[(r0 + ii) * HID + k];
      float a0 = bflo(au), a1 = bfhi(au);
      acc[ii][0] = fmaf(a1, w1x, fmaf(a0, w0x, acc[ii][0]));
      acc[ii][1] = fmaf(a1, w1y, fmaf(a0, w0y, acc[ii][1]));
      acc[ii][2] = fmaf(a1, w1z, fmaf(a0, w0z, acc[ii][2]));
      acc[ii][3] = fmaf(a1, w1w, fmaf(a0, w0w, acc[ii][3]));
    }
  }

  float4 bv = *(const float4*)&b2[c0];
#pragma unroll
  for (int ii = 0; ii < 8; ++ii) {
    int gr = R0 + r0 + ii;
    if (gr < N) {
      ushort4 o;
      o.x = f2bf(acc[ii][0] + bv.x);
      o.y = f2bf(acc[ii][1] + bv.y);
      o.z = f2bf(acc[ii][2] + bv.z);
      o.w = f2bf(acc[ii][3] + bv.w);
      *(ushort4*)&t2[(size_t)gr * HID + c0] = o;
    }
  }
}

// --------------------------- SPMM2 (128-dim bf16, full wave) ---------------
// At its line-rate floor (4 lines/edge x 3.2M / ~76 G lines/s ~= 168 us).
__global__ __launch_bounds__(256) void spmm2_kernel(
    const unsigned short* __restrict__ mat, const int* __restrict__ rows,
    const int* __restrict__ cols, const float* __restrict__ vals,
    float* __restrict__ out, int E) {
  int gw0 = (blockIdx.x * blockDim.x + threadIdx.x) >> 6;
  const int gw = __builtin_amdgcn_readfirstlane(gw0);
  const int lane = threadIdx.x & 63;
  const int nw = (gridDim.x * blockDim.x) >> 6;
  const int S = (E + nw - 1) / nw;
  int start = gw * S;
  int end = start + S;
  if (end > E) end = E;
  if (start >= end) return;

  const int d2 = lane * 2;
  float2 acc = {0.f, 0.f};
  int curRow = rows[start];

  auto flush = [&]() {
    float* o = out + (size_t)curRow * HID + d2;
    atomicAdd(o + 0, acc.x);
    atomicAdd(o + 1, acc.y);
    acc.x = 0.f;
    acc.y = 0.f;
  };

  for (int base = start; base < end; base += 64) {
    const int cnt = min(64, end - base);
    int c_ = 0, r_ = 0;
    float v_ = 0.f;
    if (lane < cnt) {
      int e = base + lane;
      c_ = cols[e];
      v_ = vals[e];
      r_ = rows[e];
    }

    int j = 0;
    for (; j + 4 <= cnt; j += 4) {
      int c0 = __shfl(c_, j + 0), c1 = __shfl(c_, j + 1);
      int c2 = __shfl(c_, j + 2), c3 = __shfl(c_, j + 3);
      float v0 = __shfl(v_, j + 0), v1 = __shfl(v_, j + 1);
      float v2 = __shfl(v_, j + 2), v3 = __shfl(v_, j + 3);
      int r0 = __shfl(r_, j + 0), r1 = __shfl(r_, j + 1);
      int r2 = __shfl(r_, j + 2), r3 = __shfl(r_, j + 3);
      unsigned u0 = *(const unsigned*)(mat + (size_t)c0 * HID + d2);
      unsigned u1 = *(const unsigned*)(mat + (size_t)c1 * HID + d2);
      unsigned u2 = *(const unsigned*)(mat + (size_t)c2 * HID + d2);
      unsigned u3 = *(const unsigned*)(mat + (size_t)c3 * HID + d2);

      if (r0 != curRow) { flush(); curRow = r0; }
      acc.x = fmaf(v0, bflo(u0), acc.x);
      acc.y = fmaf(v0, bfhi(u0), acc.y);
      if (r1 != curRow) { flush(); curRow = r1; }
      acc.x = fmaf(v1, bflo(u1), acc.x);
      acc.y = fmaf(v1, bfhi(u1), acc.y);
      if (r2 != curRow) { flush(); curRow = r2; }
      acc.x = fmaf(v2, bflo(u2), acc.x);
      acc.y = fmaf(v2, bfhi(u2), acc.y);
      if (r3 != curRow) { flush(); curRow = r3; }
      acc.x = fmaf(v3, bflo(u3), acc.x);
      acc.y = fmaf(v3, bfhi(u3), acc.y);
    }
    for (; j < cnt; ++j) {
      int c = __shfl(c_, j);
      float v = __shfl(v_, j);
      int r = __shfl(r_, j);
      if (r != curRow) { flush(); curRow = r; }
      unsigned u = *(const unsigned*)(mat + (size_t)c * HID + d2);
      acc.x = fmaf(v, bflo(u), acc.x);
      acc.y = fmaf(v, bfhi(u), acc.y);
    }
  }
  flush();
}

// --------------------------- fused attention (online softmax) --------------
__global__ __launch_bounds__(256) void att_fused_kernel(
    const unsigned short* __restrict__ h1r, const float* __restrict__ h2p,
    const float* __restrict__ attw, const float* __restrict__ attb,
    float* __restrict__ pm, float* __restrict__ pden,
    float* __restrict__ pnum, int N) {
  __shared__ float sm[4], sden[4], snum[4][HID];
  const int NB = gridDim.x;
  const int w = threadIdx.x >> 6;
  const int lane = threadIdx.x & 63;
  const int gw = blockIdx.x * 4 + w;
  const int nw = NB * 4;
  const float2 wv = *(const float2*)(attw + lane * 2);
  const float b = attb[0];

  float m = -INFINITY, den = 0.f, ax = 0.f, ay = 0.f;
  for (int n = gw; n < N; n += nw) {
    unsigned hu = *(const unsigned*)&h1r[(size_t)n * HID + lane * 2];
    float2 c = *(const float2*)&h2p[(size_t)n * HID + lane * 2];
    float hx = bflo(hu) + relu(c.x);
    float hy = bfhi(hu) + relu(c.y);
    float p = hx * wv.x + hy * wv.y;
#pragma unroll
    for (int off = 1; off < 64; off <<= 1) p += __shfl_xor(p, off);
    float sc = p + b;
    if (sc > m) {
      float scale = expf(m - sc);   // exp(-inf)=0 on first node
      den *= scale; ax *= scale; ay *= scale;
      m = sc;
    }
    float e = expf(sc - m);
    den += e;
    ax = fmaf(e, hx, ax);
    ay = fmaf(e, hy, ay);
  }

  if (lane == 0) { sm[w] = m; sden[w] = den; }
  snum[w][lane * 2] = ax;
  snum[w][lane * 2 + 1] = ay;
  __syncthreads();

  const int t = threadIdx.x;
  if (t < HID) {
    float M4 = fmaxf(fmaxf(sm[0], sm[1]), fmaxf(sm[2], sm[3]));
    float s0 = expf(sm[0] - M4), s1 = expf(sm[1] - M4);
    float s2 = expf(sm[2] - M4), s3 = expf(sm[3] - M4);
    float nv = snum[0][t] * s0 + snum[1][t] * s1 + snum[2][t] * s2 +
               snum[3][t] * s3;
    pnum[(size_t)t * NB + blockIdx.x] = nv;
    if (t == 0) {
      pden[blockIdx.x] = sden[0] * s0 + sden[1] * s1 + sden[2] * s2 +
                         sden[3] * s3;
      pm[blockIdx.x] = M4;
    }
  }
}

// --------------------------- combine partials + classifier -----------------
__global__ __launch_bounds__(1024) void att_combine_kernel(
    const float* __restrict__ pm, const float* __restrict__ pden,
    const float* __restrict__ pnum, const float* __restrict__ clsw,
    const float* __restrict__ clsb, float* __restrict__ out, int NB) {
  __shared__ float red[1024];
  __shared__ float scale[1024];
  __shared__ float g[HID + 1];  // [0..127]=num, [128]=den
  const int t = threadIdx.x;

  float v = pm[t];
  red[t] = v;
  __syncthreads();
  for (int off = 512; off > 0; off >>= 1) {
    if (t < off) red[t] = fmaxf(red[t], red[t + off]);
    __syncthreads();
  }
  const float M = red[0];
  __syncthreads();

  scale[t] = expf(v - M);
  red[t] = pden[t] * scale[t];
  __syncthreads();
  for (int off = 512; off > 0; off >>= 1) {
    if (t < off) red[t] += red[t + off];
    __syncthreads();
  }
  if (t == 0) g[HID] = red[0];

  const int c = t >> 3, bb = t & 7;
  float acc = 0.f;
  for (int b2 = bb; b2 < NB; b2 += 8) acc += pnum[(size_t)c * NB + b2] * scale[b2];
  acc += __shfl_down(acc, 4);
  acc += __shfl_down(acc, 2);
  acc += __shfl_down(acc, 1);
  if (bb == 0) g[c] = acc;
  __syncthreads();

  if (t < 10) {
    float o = 0.f;
    for (int d = 0; d < HID; ++d) o = fmaf(g[d], clsw[d * 10 + t], o);
    out[t] = clsb[t] + o / g[HID];
  }
}

extern "C" void kernel_launch(void* const* d_in, const int* in_sizes, int n_in,
                              void* d_out, int out_size, void* d_ws,
                              size_t ws_size, hipStream_t stream) {
  const float* x = (const float*)d_in[0];
  const int* erows = (const int*)d_in[1];
  const int* ecols = (const int*)d_in[2];
  const float* evals = (const float*)d_in[3];
  const float* fc1w = (const float*)d_in[4];
  const float* fc1b = (const float*)d_in[5];
  const float* fc2w = (const float*)d_in[6];
  const float* fc2b = (const float*)d_in[7];
  const float* attw = (const float*)d_in[8];
  const float* attb = (const float*)d_in[9];
  const float* clsw = (const float*)d_in[10];
  const float* clsb = (const float*)d_in[11];
  float* out = (float*)d_out;

  const int N = in_sizes[0] / 64;   // 100000
  const int E = in_sizes[1];        // 3200000
  const int NB = 1024;              // attention partial blocks

  char* base = (char*)d_ws;
  float* ax = (float*)base;                                      // N*64 f32
  float* h2p = (float*)(base + (size_t)N * 64 * 4);              // N*128 f32
  float* rs = (float*)(base + (size_t)N * (64 + 128) * 4);       // N f32
  unsigned short* xb = (unsigned short*)(base + (size_t)N * (64 + 128 + 1) * 4);
  unsigned short* t2 = (unsigned short*)((char*)xb + (size_t)N * 64 * 2);
  unsigned short* h1r = (unsigned short*)((char*)t2 + (size_t)N * HID * 2);
  float* pm = (float*)((char*)h1r + (size_t)N * HID * 2);        // NB
  float* pden = pm + NB;                                         // NB
  float* pnum = pden + NB;                                       // 128*NB

  const int nblk = (N + 63) / 64;

  // Zero accumulators: ax | h2p | rs are contiguous.
  hipMemsetAsync(ax, 0, (size_t)N * (64 + 128 + 1) * 4, stream);

  cast_x_kernel<<<(N * 64 / 4 + 255) / 256, 256, 0, stream>>>(x, xb, N * 16);
  spmm1_kernel<<<2048, 256, 0, stream>>>(xb, erows, ecols, evals, ax, rs, E);
  gemm1_kernel<<<nblk, 256, 0, stream>>>(ax, fc1w, fc1b, rs, h1r, N);
  gemm2_kernel<<<nblk, 256, 0, stream>>>(h1r, fc2w, fc2b, t2, N);
  spmm2_kernel<<<2048, 256, 0, stream>>>(t2, erows, ecols, evals, h2p, E);
  att_fused_kernel<<<NB, 256, 0, stream>>>(h1r, h2p, attw, attb, pm, pden,
                                           pnum, N);
  att_combine_kernel<<<1, 1024, 0, stream>>>(pm, pden, pnum, clsw, clsb, out,
                                             NB);
}